// Round 1
// baseline (11098.978 us; speedup 1.0000x reference)
//
#include <hip/hip_runtime.h>

#define Bsz 1024
#define Tn  200
#define Dd  64
#define Ld  256
#define Hd  256

#define ROWS   16          // batch rows per workgroup -> 64 WGs
#define NWAVE  8           // waves per WG (512 threads)
#define NTILE  2           // 16-col output tiles per wave (8*2*16 = 256 cols)
#define SA     264         // bf16 row stride for activation LDS (528B = odd*16B)
#define SX     72          // bf16 row stride for x tile

typedef __attribute__((ext_vector_type(8))) short  short8;
typedef __attribute__((ext_vector_type(4))) float  floatx4;

// workspace layout (bytes)
#define OFF_WIH 0
#define OFF_WHH (OFF_WIH + 3*Ld*Dd*2)   // 98304
#define OFF_W1M (OFF_WHH + 3*Ld*Ld*2)   // 491520
#define OFF_W2  (OFF_W1M + Hd*Ld*2)     // 622592
#define OFF_W3  (OFF_W2  + Hd*Hd*2)     // 753664
#define OFF_W1L (OFF_W3  + Ld*Hd*2)     // 884736 (fp32 last column of W1)

__device__ __forceinline__ short f2bf(float f) {
    union { float f; unsigned u; } v; v.f = f;
    unsigned r = v.u + 0x7fffu + ((v.u >> 16) & 1u);   // RNE
    return (short)(r >> 16);
}
__device__ __forceinline__ float sig_(float x) {
    float e = __expf(-x);                 // x->-inf: e=inf, rcp(1+inf)=0  (safe)
    return __builtin_amdgcn_rcpf(1.f + e);
}
__device__ __forceinline__ float tanh_(float x) {
    float xc = fminf(fmaxf(x, -15.f), 15.f);
    float e  = __expf(2.f * xc);
    return (e - 1.f) * __builtin_amdgcn_rcpf(e + 1.f);
}
__device__ __forceinline__ floatx4 mfma_(short8 a, short8 b, floatx4 c) {
    return __builtin_amdgcn_mfma_f32_16x16x32_bf16(a, b, c, 0, 0, 0);
}

// ---------------- weight prep: fp32 -> bf16 into d_ws ----------------
__global__ void prep_kernel(const float* __restrict__ Wih,
                            const float* __restrict__ Whh,
                            const float* __restrict__ W1,
                            const float* __restrict__ W2,
                            const float* __restrict__ W3,
                            char* __restrict__ ws)
{
    short* wih = (short*)(ws + OFF_WIH);
    short* whh = (short*)(ws + OFF_WHH);
    short* w1m = (short*)(ws + OFF_W1M);
    short* w2m = (short*)(ws + OFF_W2);
    short* w3m = (short*)(ws + OFF_W3);
    float* w1l = (float*)(ws + OFF_W1L);
    const int stride = gridDim.x * blockDim.x;
    const int i0 = blockIdx.x * blockDim.x + threadIdx.x;
    for (int i = i0; i < 3*Ld*Dd; i += stride) wih[i] = f2bf(Wih[i]);
    for (int i = i0; i < 3*Ld*Ld; i += stride) whh[i] = f2bf(Whh[i]);
    for (int i = i0; i < Hd*Ld;   i += stride) {
        int n = i / Ld, k = i - n*Ld;
        w1m[i] = f2bf(W1[n*(Ld+1) + k]);
    }
    for (int i = i0; i < Hd;      i += stride) w1l[i] = W1[i*(Ld+1) + Ld];
    for (int i = i0; i < Hd*Hd;   i += stride) w2m[i] = f2bf(W2[i]);
    for (int i = i0; i < Ld*Hd;   i += stride) w3m[i] = f2bf(W3[i]);
}

// ---------------- persistent ODE-RNN kernel ----------------
__global__ __launch_bounds__(NWAVE*64) void odernn_kernel(
    const float* __restrict__ x,    const float* __restrict__ tarr,
    const float* __restrict__ mask,
    const float* __restrict__ b_ih, const float* __restrict__ b_hh,
    const float* __restrict__ b1v,  const float* __restrict__ b2v,
    const float* __restrict__ b3v,  const char* __restrict__ ws,
    float* __restrict__ out)
{
    __shared__ __attribute__((aligned(16))) short ays[ROWS*SA]; // bf16 mirror of state / stage input
    __shared__ __attribute__((aligned(16))) short bu [ROWS*SA]; // MLP layer-1 out
    __shared__ __attribute__((aligned(16))) short cv [ROWS*SA]; // MLP layer-2 out
    __shared__ __attribute__((aligned(16))) short xb [ROWS*SX]; // x tile
    __shared__ float maskv[ROWS];

    const short* Wih = (const short*)(ws + OFF_WIH);
    const short* Whh = (const short*)(ws + OFF_WHH);
    const short* W1m = (const short*)(ws + OFF_W1M);
    const short* W2m = (const short*)(ws + OFF_W2);
    const short* W3m = (const short*)(ws + OFF_W3);
    const float* W1l = (const float*)(ws + OFF_W1L);

    const int tid  = threadIdx.x;
    const int wv   = tid >> 6;
    const int lane = tid & 63;
    const int quad = lane >> 4;
    const int c16  = lane & 15;
    const int koff = quad * 8;
    const int b0   = blockIdx.x * ROWS;

    // per-lane loop-invariant columns and biases
    int   ccol[NTILE];
    float bir[NTILE], biz[NTILE], bin_[NTILE], bhn[NTILE];
    float b1c[NTILE], b2c[NTILE], b3c[NTILE], w1lc[NTILE];
#pragma unroll
    for (int j = 0; j < NTILE; ++j) {
        int c = wv * (16*NTILE) + j*16 + c16;
        ccol[j] = c;
        bir[j]  = b_ih[c]        + b_hh[c];
        biz[j]  = b_ih[Ld + c]   + b_hh[Ld + c];
        bin_[j] = b_ih[2*Ld + c];
        bhn[j]  = b_hh[2*Ld + c];
        b1c[j]  = b1v[c]; b2c[j] = b2v[c]; b3c[j] = b3v[c];
        w1lc[j] = W1l[c];
    }

    // fp32 hidden state: lane owns (row=quad*4+i, col=ccol[j])
    float hreg[NTILE][4];
#pragma unroll
    for (int j = 0; j < NTILE; ++j)
#pragma unroll
        for (int i = 0; i < 4; ++i) hreg[j][i] = 0.f;

    for (int i = tid; i < ROWS*SA; i += NWAVE*64) ays[i] = 0;  // bf16(h=0)
    __syncthreads();

    for (int t = 0; t < Tn; ++t) {
        // ---- stage x tile + mask ----
        for (int i = tid; i < ROWS*Dd; i += NWAVE*64) {
            int r = i >> 6, d = i & 63;
            xb[r*SX + d] = f2bf(x[((size_t)(b0 + r)*Tn + t)*Dd + d]);
        }
        if (tid < ROWS) maskv[tid] = mask[(size_t)(b0 + tid)*Tn + t];
        __syncthreads();

        // ---- GRU: gates for this lane's columns ----
        floatx4 ar[NTILE], az[NTILE], ain[NTILE], ahn[NTILE];
#pragma unroll
        for (int j = 0; j < NTILE; ++j) {
            floatx4 z = {0.f,0.f,0.f,0.f};
            ar[j] = z; az[j] = z; ain[j] = z; ahn[j] = z;
        }
        // x-part (K=64)
#pragma unroll
        for (int ks = 0; ks < 2; ++ks) {
            short8 a = *(const short8*)&xb[c16*SX + ks*32 + koff];
#pragma unroll
            for (int j = 0; j < NTILE; ++j) {
                short8 br = *(const short8*)&Wih[(0*Ld + ccol[j])*Dd + ks*32 + koff];
                short8 bz = *(const short8*)&Wih[(1*Ld + ccol[j])*Dd + ks*32 + koff];
                short8 bn = *(const short8*)&Wih[(2*Ld + ccol[j])*Dd + ks*32 + koff];
                ar[j]  = mfma_(a, br, ar[j]);
                az[j]  = mfma_(a, bz, az[j]);
                ain[j] = mfma_(a, bn, ain[j]);
            }
        }
        // h-part (K=256)
#pragma unroll 2
        for (int ks = 0; ks < 8; ++ks) {
            short8 a = *(const short8*)&ays[c16*SA + ks*32 + koff];
#pragma unroll
            for (int j = 0; j < NTILE; ++j) {
                short8 br = *(const short8*)&Whh[(0*Ld + ccol[j])*Ld + ks*32 + koff];
                short8 bz = *(const short8*)&Whh[(1*Ld + ccol[j])*Ld + ks*32 + koff];
                short8 bn = *(const short8*)&Whh[(2*Ld + ccol[j])*Ld + ks*32 + koff];
                ar[j]  = mfma_(a, br, ar[j]);
                az[j]  = mfma_(a, bz, az[j]);
                ahn[j] = mfma_(a, bn, ahn[j]);
            }
        }
        __syncthreads();   // all waves done reading ays before overwrite

        const float t0 = tarr[t];
        // GRU epilogue: gates, mask gating, write h_obs (state + LDS mirror + out)
#pragma unroll
        for (int j = 0; j < NTILE; ++j) {
#pragma unroll
            for (int i = 0; i < 4; ++i) {
                int   row  = quad*4 + i;
                float hold = hreg[j][i];
                float r = sig_(ar[j][i] + bir[j]);
                float z = sig_(az[j][i] + biz[j]);
                float n = tanh_(ain[j][i] + bin_[j] + r*(ahn[j][i] + bhn[j]));
                float hnew = (1.f - z)*n + z*hold;
                float m = maskv[row];
                float hobs = m*hnew + (1.f - m)*hold;
                hreg[j][i] = hobs;
                ays[row*SA + ccol[j]] = f2bf(hobs);
                out[((size_t)(b0+row)*Tn + t)*Ld + ccol[j]] = hobs;
            }
        }
        __syncthreads();   // ays(h_obs) ready for ODE (or next GRU at t=Tn-1... break)

        if (t == Tn - 1) break;   // last step: GRU only (h_fin), no integration

        const float t1 = tarr[t+1];
        const float dt = (t1 - t0) * 0.25f;
        float kacc[NTILE][4];

#pragma unroll 1
        for (int sub = 0; sub < 4; ++sub) {
            const float tt = t0 + dt * (float)sub;
#pragma unroll
            for (int j = 0; j < NTILE; ++j)
#pragma unroll
                for (int i = 0; i < 4; ++i) kacc[j][i] = 0.f;

#pragma unroll 1
            for (int s = 0; s < 4; ++s) {
                const float tv = tt + ((s==0) ? 0.f : (s==3) ? dt : 0.5f*dt);
                floatx4 acc[NTILE];

                // ---- L1: u = tanh(y @ W1m^T + tv*w1last + b1) ----
#pragma unroll
                for (int j = 0; j < NTILE; ++j) { floatx4 z = {0.f,0.f,0.f,0.f}; acc[j] = z; }
#pragma unroll
                for (int ks = 0; ks < 8; ++ks) {
                    short8 a = *(const short8*)&ays[c16*SA + ks*32 + koff];
#pragma unroll
                    for (int j = 0; j < NTILE; ++j) {
                        short8 b = *(const short8*)&W1m[ccol[j]*Ld + ks*32 + koff];
                        acc[j] = mfma_(a, b, acc[j]);
                    }
                }
#pragma unroll
                for (int j = 0; j < NTILE; ++j)
#pragma unroll
                    for (int i = 0; i < 4; ++i) {
                        float u = tanh_(acc[j][i] + tv*w1lc[j] + b1c[j]);
                        bu[(quad*4+i)*SA + ccol[j]] = f2bf(u);
                    }
                __syncthreads();

                // ---- L2: v = tanh(u @ W2^T + b2) ----
#pragma unroll
                for (int j = 0; j < NTILE; ++j) { floatx4 z = {0.f,0.f,0.f,0.f}; acc[j] = z; }
#pragma unroll
                for (int ks = 0; ks < 8; ++ks) {
                    short8 a = *(const short8*)&bu[c16*SA + ks*32 + koff];
#pragma unroll
                    for (int j = 0; j < NTILE; ++j) {
                        short8 b = *(const short8*)&W2m[ccol[j]*Hd + ks*32 + koff];
                        acc[j] = mfma_(a, b, acc[j]);
                    }
                }
#pragma unroll
                for (int j = 0; j < NTILE; ++j)
#pragma unroll
                    for (int i = 0; i < 4; ++i) {
                        float v = tanh_(acc[j][i] + b2c[j]);
                        cv[(quad*4+i)*SA + ccol[j]] = f2bf(v);
                    }
                __syncthreads();

                // ---- L3: k = v @ W3^T + b3 ; RK4 bookkeeping ----
#pragma unroll
                for (int j = 0; j < NTILE; ++j) { floatx4 z = {0.f,0.f,0.f,0.f}; acc[j] = z; }
#pragma unroll
                for (int ks = 0; ks < 8; ++ks) {
                    short8 a = *(const short8*)&cv[c16*SA + ks*32 + koff];
#pragma unroll
                    for (int j = 0; j < NTILE; ++j) {
                        short8 b = *(const short8*)&W3m[ccol[j]*Hd + ks*32 + koff];
                        acc[j] = mfma_(a, b, acc[j]);
                    }
                }
                // ays was last read in L1 (two barriers ago) -> safe to overwrite
                {
                    const float wst  = (s==1 || s==2) ? 2.f : 1.f;
                    const float coef = (s==2) ? dt : 0.5f*dt;    // stage-input coefficient (s<3)
#pragma unroll
                    for (int j = 0; j < NTILE; ++j)
#pragma unroll
                        for (int i = 0; i < 4; ++i) {
                            float k = acc[j][i] + b3c[j];
                            kacc[j][i] += wst * k;
                            float ynext;
                            if (s < 3) {
                                ynext = hreg[j][i] + coef * k;
                            } else {
                                ynext = hreg[j][i] + (dt * (1.f/6.f)) * kacc[j][i];
                                hreg[j][i] = ynext;              // advance fp32 state
                            }
                            ays[(quad*4+i)*SA + ccol[j]] = f2bf(ynext);
                        }
                }
                __syncthreads();   // next stage / substep reads ays
            } // stages
        } // substeps
    } // t
}

extern "C" void kernel_launch(void* const* d_in, const int* in_sizes, int n_in,
                              void* d_out, int out_size, void* d_ws, size_t ws_size,
                              hipStream_t stream) {
    (void)in_sizes; (void)n_in; (void)out_size; (void)ws_size;
    const float* x    = (const float*)d_in[0];
    const float* tarr = (const float*)d_in[1];
    const float* mask = (const float*)d_in[2];
    const float* Wih  = (const float*)d_in[3];
    const float* Whh  = (const float*)d_in[4];
    const float* bih  = (const float*)d_in[5];
    const float* bhh  = (const float*)d_in[6];
    const float* W1   = (const float*)d_in[7];
    const float* b1   = (const float*)d_in[8];
    const float* W2   = (const float*)d_in[9];
    const float* b2   = (const float*)d_in[10];
    const float* W3   = (const float*)d_in[11];
    const float* b3   = (const float*)d_in[12];
    float* out = (float*)d_out;
    char*  ws  = (char*)d_ws;

    hipLaunchKernelGGL(prep_kernel, dim3(256), dim3(256), 0, stream,
                       Wih, Whh, W1, W2, W3, ws);
    hipLaunchKernelGGL(odernn_kernel, dim3(Bsz/ROWS), dim3(NWAVE*64), 0, stream,
                       x, tarr, mask, bih, bhh, b1, b2, b3, ws, out);
}

// Round 2
// 8839.121 us; speedup vs baseline: 1.2557x; 1.2557x over previous
//
#include <hip/hip_runtime.h>

#define Bsz 1024
#define Tn  200
#define Dd  64
#define Ld  256
#define Hd  256

#define ROWS   16          // batch rows per workgroup -> 64 WGs
#define NWAVE  8           // waves per WG (512 threads)
#define NTILE  2           // 16-col output tiles per wave (8*2*16 = 256 cols)
#define SA     264         // bf16 row stride for activation LDS
#define SX     72          // bf16 row stride for x tile

typedef __attribute__((ext_vector_type(8))) short  short8;
typedef __attribute__((ext_vector_type(4))) float  floatx4;

// workspace layout (bytes)
#define OFF_W1B  0                         // W1 block layout (LDS image)   131072
#define OFF_W1L  (OFF_W1B + Ld*Ld*2)       // fp32 last col of W1            1024
#define OFF_W2R  (OFF_W1L + Hd*4)          // W2 per-wave reg layout        131072
#define OFF_W3R  (OFF_W2R + Hd*Hd*2)       // W3 per-wave reg layout        131072
#define OFF_WIHR (OFF_W3R + Ld*Hd*2)       // Wih per-wave layout            98304
#define OFF_WHHR (OFF_WIHR + 3*Ld*Dd*2)    // Whh per-wave layout           393216

__device__ __forceinline__ short f2bf(float f) {
    union { float f; unsigned u; } v; v.f = f;
    unsigned r = v.u + 0x7fffu + ((v.u >> 16) & 1u);   // RNE
    return (short)(r >> 16);
}
__device__ __forceinline__ float sig_(float x) {
    float e = __expf(-x);
    return __builtin_amdgcn_rcpf(1.f + e);
}
__device__ __forceinline__ float tanh_(float x) {
    float xc = fminf(fmaxf(x, -15.f), 15.f);
    float e  = __expf(2.f * xc);
    return (e - 1.f) * __builtin_amdgcn_rcpf(e + 1.f);
}
__device__ __forceinline__ floatx4 mfma_(short8 a, short8 b, floatx4 c) {
    return __builtin_amdgcn_mfma_f32_16x16x32_bf16(a, b, c, 0, 0, 0);
}

// ---------------- weight prep: fp32 -> bf16, reordered layouts ----------------
__global__ void prep_kernel(const float* __restrict__ Wih,
                            const float* __restrict__ Whh,
                            const float* __restrict__ W1,
                            const float* __restrict__ W2,
                            const float* __restrict__ W3,
                            char* __restrict__ ws)
{
    short* w1b  = (short*)(ws + OFF_W1B);
    float* w1l  = (float*)(ws + OFF_W1L);
    short* w2r  = (short*)(ws + OFF_W2R);
    short* w3r  = (short*)(ws + OFF_W3R);
    short* wihr = (short*)(ws + OFF_WIHR);
    short* whhr = (short*)(ws + OFF_WHHR);
    const int i0 = blockIdx.x * blockDim.x + threadIdx.x;
    const int stride = gridDim.x * blockDim.x;

    // W1 block layout: idx = ((nb*8+ks)*64 + lane)*8 + j
    for (int idx = i0; idx < Ld*Ld; idx += stride) {
        int j = idx & 7, t = idx >> 3;
        int lane = t & 63; t >>= 6;
        int ks = t & 7, nb = t >> 3;
        int c16 = lane & 15, quad = lane >> 4;
        int col = nb*16 + c16, k = ks*32 + quad*8 + j;
        w1b[idx] = f2bf(W1[col*(Ld+1) + k]);
    }
    for (int i = i0; i < Hd; i += stride) w1l[i] = W1[i*(Ld+1) + Ld];

    // W2R/W3R: idx = (((wv*2+jt)*8+ks)*64 + lane)*8 + jj
    for (int idx = i0; idx < Hd*Hd; idx += stride) {
        int jj = idx & 7, t = idx >> 3;
        int lane = t & 63; t >>= 6;
        int ks = t & 7; t >>= 3;
        int jt = t & 1, wv = t >> 1;
        int c16 = lane & 15, quad = lane >> 4;
        int col = wv*32 + jt*16 + c16, k = ks*32 + quad*8 + jj;
        w2r[idx] = f2bf(W2[col*Hd + k]);
        w3r[idx] = f2bf(W3[col*Hd + k]);
    }
    // WIHR: idx = ((((g*8+wv)*2+jt)*2+ks)*64 + lane)*8 + jj   (ks<2)
    for (int idx = i0; idx < 3*Ld*Dd; idx += stride) {
        int jj = idx & 7, t = idx >> 3;
        int lane = t & 63; t >>= 6;
        int ks = t & 1; t >>= 1;
        int jt = t & 1; t >>= 1;
        int wv = t & 7, g = t >> 3;
        int c16 = lane & 15, quad = lane >> 4;
        int col = wv*32 + jt*16 + c16, k = ks*32 + quad*8 + jj;
        wihr[idx] = f2bf(Wih[(g*Ld + col)*Dd + k]);
    }
    // WHHR: idx = ((((g*8+wv)*2+jt)*8+ks)*64 + lane)*8 + jj
    for (int idx = i0; idx < 3*Ld*Ld; idx += stride) {
        int jj = idx & 7, t = idx >> 3;
        int lane = t & 63; t >>= 6;
        int ks = t & 7; t >>= 3;
        int jt = t & 1; t >>= 1;
        int wv = t & 7, g = t >> 3;
        int c16 = lane & 15, quad = lane >> 4;
        int col = wv*32 + jt*16 + c16, k = ks*32 + quad*8 + jj;
        whhr[idx] = f2bf(Whh[(g*Ld + col)*Ld + k]);
    }
}

// ---------------- persistent ODE-RNN kernel ----------------
__global__ __launch_bounds__(NWAVE*64, 2) void odernn_kernel(
    const float* __restrict__ x,    const float* __restrict__ tarr,
    const float* __restrict__ mask,
    const float* __restrict__ b_ih, const float* __restrict__ b_hh,
    const float* __restrict__ b1v,  const float* __restrict__ b2v,
    const float* __restrict__ b3v,  const char* __restrict__ ws,
    float* __restrict__ out)
{
    extern __shared__ __attribute__((aligned(16))) short smem[];
    short* w1s = smem;                     // 65536 shorts (128 KB), block layout
    short* ays = w1s + Ld*Ld;              // 16*SA
    short* bu  = ays + ROWS*SA;
    short* cv  = bu  + ROWS*SA;
    short* xb  = cv  + ROWS*SA;            // 16*SX
    float* maskv = (float*)(xb + ROWS*SX); // 16 floats

    const short* W2R  = (const short*)(ws + OFF_W2R);
    const short* W3R  = (const short*)(ws + OFF_W3R);
    const short* WIHR = (const short*)(ws + OFF_WIHR);
    const short* WHHR = (const short*)(ws + OFF_WHHR);
    const float* W1l  = (const float*)(ws + OFF_W1L);

    const int tid  = threadIdx.x;
    const int wv   = tid >> 6;
    const int lane = tid & 63;
    const int quad = lane >> 4;
    const int c16  = lane & 15;
    const int koff = quad * 8;
    const int b0   = blockIdx.x * ROWS;

    // copy W1 into LDS (lane-linear block layout, conflict-free reads later)
    {
        const short8* src = (const short8*)(ws + OFF_W1B);
        short8* dst = (short8*)w1s;
        for (int i = tid; i < (Ld*Ld)/8; i += NWAVE*64) dst[i] = src[i];
    }
    // preload W2/W3 slices into registers: 16 short8 each = 128 VGPRs total
    short8 w2r[NTILE][8], w3r[NTILE][8];
#pragma unroll
    for (int jt = 0; jt < NTILE; ++jt)
#pragma unroll
        for (int ks = 0; ks < 8; ++ks) {
            int off = (((wv*NTILE + jt)*8 + ks)*64 + lane)*8;
            w2r[jt][ks] = *(const short8*)(W2R + off);
            w3r[jt][ks] = *(const short8*)(W3R + off);
        }

    // per-lane loop-invariant columns and biases
    int   ccol[NTILE];
    float bir[NTILE], biz[NTILE], bin_[NTILE], bhn[NTILE];
    float b1c[NTILE], b2c[NTILE], b3c[NTILE], w1lc[NTILE];
#pragma unroll
    for (int jt = 0; jt < NTILE; ++jt) {
        int c = wv * (16*NTILE) + jt*16 + c16;
        ccol[jt] = c;
        bir[jt]  = b_ih[c]        + b_hh[c];
        biz[jt]  = b_ih[Ld + c]   + b_hh[Ld + c];
        bin_[jt] = b_ih[2*Ld + c];
        bhn[jt]  = b_hh[2*Ld + c];
        b1c[jt]  = b1v[c]; b2c[jt] = b2v[c]; b3c[jt] = b3v[c];
        w1lc[jt] = W1l[c];
    }

    // fp32 hidden state: lane owns (row=quad*4+i, col=ccol[jt])
    float hreg[NTILE][4];
#pragma unroll
    for (int jt = 0; jt < NTILE; ++jt)
#pragma unroll
        for (int i = 0; i < 4; ++i) hreg[jt][i] = 0.f;

    for (int i = tid; i < ROWS*SA; i += NWAVE*64) ays[i] = 0;  // bf16(h=0)
    __syncthreads();

    for (int t = 0; t < Tn; ++t) {
        // ---- stage x tile + mask ----
        for (int i = tid; i < ROWS*Dd; i += NWAVE*64) {
            int r = i >> 6, d = i & 63;
            xb[r*SX + d] = f2bf(x[((size_t)(b0 + r)*Tn + t)*Dd + d]);
        }
        if (tid < ROWS) maskv[tid] = mask[(size_t)(b0 + tid)*Tn + t];
        __syncthreads();

        // ---- GRU: per-tile to limit live registers ----
        floatx4 ar[NTILE], az[NTILE], ain[NTILE], ahn[NTILE];
#pragma unroll
        for (int jt = 0; jt < NTILE; ++jt) {
            floatx4 z4 = {0.f,0.f,0.f,0.f};
            ar[jt] = z4; az[jt] = z4; ain[jt] = z4; ahn[jt] = z4;
            // x-part (K=64), coalesced lane-linear weight loads
#pragma unroll
            for (int ks = 0; ks < 2; ++ks) {
                short8 a = *(const short8*)&xb[c16*SX + ks*32 + koff];
                const short* p = WIHR + wv*2048 + jt*1024 + ks*512 + lane*8;
                short8 brv = *(const short8*)(p);
                short8 bzv = *(const short8*)(p + 16384);
                short8 bnv = *(const short8*)(p + 32768);
                ar[jt]  = mfma_(a, brv, ar[jt]);
                az[jt]  = mfma_(a, bzv, az[jt]);
                ain[jt] = mfma_(a, bnv, ain[jt]);
            }
            // h-part (K=256)
#pragma unroll 2
            for (int ks = 0; ks < 8; ++ks) {
                short8 a = *(const short8*)&ays[c16*SA + ks*32 + koff];
                const short* p = WHHR + wv*8192 + jt*4096 + ks*512 + lane*8;
                short8 brv = *(const short8*)(p);
                short8 bzv = *(const short8*)(p + 65536);
                short8 bnv = *(const short8*)(p + 131072);
                ar[jt]  = mfma_(a, brv, ar[jt]);
                az[jt]  = mfma_(a, bzv, az[jt]);
                ahn[jt] = mfma_(a, bnv, ahn[jt]);
            }
        }
        __syncthreads();   // all waves done reading ays before overwrite

        const float t0 = tarr[t];
        // GRU epilogue: gates, mask gating, write h_obs (state + LDS mirror + out)
#pragma unroll
        for (int jt = 0; jt < NTILE; ++jt) {
#pragma unroll
            for (int i = 0; i < 4; ++i) {
                int   row  = quad*4 + i;
                float hold = hreg[jt][i];
                float r = sig_(ar[jt][i] + bir[jt]);
                float z = sig_(az[jt][i] + biz[jt]);
                float n = tanh_(ain[jt][i] + bin_[jt] + r*(ahn[jt][i] + bhn[jt]));
                float hnew = (1.f - z)*n + z*hold;
                float m = maskv[row];
                float hobs = m*hnew + (1.f - m)*hold;
                hreg[jt][i] = hobs;
                ays[row*SA + ccol[jt]] = f2bf(hobs);
                out[((size_t)(b0+row)*Tn + t)*Ld + ccol[jt]] = hobs;
            }
        }
        __syncthreads();   // ays(h_obs) ready

        if (t == Tn - 1) break;   // last step: GRU only (h_fin)

        const float t1 = tarr[t+1];
        const float dt = (t1 - t0) * 0.25f;
        float kacc[NTILE][4];

#pragma unroll 1
        for (int sub = 0; sub < 4; ++sub) {
            const float tt = t0 + dt * (float)sub;
#pragma unroll
            for (int jt = 0; jt < NTILE; ++jt)
#pragma unroll
                for (int i = 0; i < 4; ++i) kacc[jt][i] = 0.f;

#pragma unroll 1
            for (int s = 0; s < 4; ++s) {
                const float tv = tt + ((s==0) ? 0.f : (s==3) ? dt : 0.5f*dt);
                floatx4 acc[NTILE];

                // ---- L1: u = tanh(y @ W1^T + tv*w1last + b1), W1 from LDS ----
#pragma unroll
                for (int jt = 0; jt < NTILE; ++jt) { floatx4 z4 = {0.f,0.f,0.f,0.f}; acc[jt] = z4; }
#pragma unroll
                for (int ks = 0; ks < 8; ++ks) {
                    short8 a = *(const short8*)&ays[c16*SA + ks*32 + koff];
#pragma unroll
                    for (int jt = 0; jt < NTILE; ++jt) {
                        short8 b = *(const short8*)&w1s[wv*8192 + jt*4096 + ks*512 + lane*8];
                        acc[jt] = mfma_(a, b, acc[jt]);
                    }
                }
#pragma unroll
                for (int jt = 0; jt < NTILE; ++jt)
#pragma unroll
                    for (int i = 0; i < 4; ++i) {
                        float u = tanh_(acc[jt][i] + tv*w1lc[jt] + b1c[jt]);
                        bu[(quad*4+i)*SA + ccol[jt]] = f2bf(u);
                    }
                __syncthreads();

                // ---- L2: v = tanh(u @ W2^T + b2), W2 in registers ----
#pragma unroll
                for (int jt = 0; jt < NTILE; ++jt) { floatx4 z4 = {0.f,0.f,0.f,0.f}; acc[jt] = z4; }
#pragma unroll
                for (int ks = 0; ks < 8; ++ks) {
                    short8 a = *(const short8*)&bu[c16*SA + ks*32 + koff];
#pragma unroll
                    for (int jt = 0; jt < NTILE; ++jt)
                        acc[jt] = mfma_(a, w2r[jt][ks], acc[jt]);
                }
#pragma unroll
                for (int jt = 0; jt < NTILE; ++jt)
#pragma unroll
                    for (int i = 0; i < 4; ++i) {
                        float v = tanh_(acc[jt][i] + b2c[jt]);
                        cv[(quad*4+i)*SA + ccol[jt]] = f2bf(v);
                    }
                __syncthreads();

                // ---- L3: k = v @ W3^T + b3, W3 in registers; RK4 bookkeeping ----
#pragma unroll
                for (int jt = 0; jt < NTILE; ++jt) { floatx4 z4 = {0.f,0.f,0.f,0.f}; acc[jt] = z4; }
#pragma unroll
                for (int ks = 0; ks < 8; ++ks) {
                    short8 a = *(const short8*)&cv[c16*SA + ks*32 + koff];
#pragma unroll
                    for (int jt = 0; jt < NTILE; ++jt)
                        acc[jt] = mfma_(a, w3r[jt][ks], acc[jt]);
                }
                // ays was last read in L1 (two barriers ago) -> safe to overwrite
                {
                    const float wst  = (s==1 || s==2) ? 2.f : 1.f;
                    const float coef = (s==2) ? dt : 0.5f*dt;
#pragma unroll
                    for (int jt = 0; jt < NTILE; ++jt)
#pragma unroll
                        for (int i = 0; i < 4; ++i) {
                            float k = acc[jt][i] + b3c[jt];
                            kacc[jt][i] += wst * k;
                            float ynext;
                            if (s < 3) {
                                ynext = hreg[jt][i] + coef * k;
                            } else {
                                ynext = hreg[jt][i] + (dt * (1.f/6.f)) * kacc[jt][i];
                                hreg[jt][i] = ynext;
                            }
                            ays[(quad*4+i)*SA + ccol[jt]] = f2bf(ynext);
                        }
                }
                __syncthreads();
            } // stages
        } // substeps
    } // t
}

extern "C" void kernel_launch(void* const* d_in, const int* in_sizes, int n_in,
                              void* d_out, int out_size, void* d_ws, size_t ws_size,
                              hipStream_t stream) {
    (void)in_sizes; (void)n_in; (void)out_size; (void)ws_size;
    const float* x    = (const float*)d_in[0];
    const float* tarr = (const float*)d_in[1];
    const float* mask = (const float*)d_in[2];
    const float* Wih  = (const float*)d_in[3];
    const float* Whh  = (const float*)d_in[4];
    const float* bih  = (const float*)d_in[5];
    const float* bhh  = (const float*)d_in[6];
    const float* W1   = (const float*)d_in[7];
    const float* b1   = (const float*)d_in[8];
    const float* W2   = (const float*)d_in[9];
    const float* b2   = (const float*)d_in[10];
    const float* W3   = (const float*)d_in[11];
    const float* b3   = (const float*)d_in[12];
    float* out = (float*)d_out;
    char*  ws  = (char*)d_ws;

    // 128KB W1 + 3 activation buffers + x tile + mask = 158,784 B dynamic LDS
    const int smem_bytes = (Ld*Ld + 3*ROWS*SA + ROWS*SX) * 2 + ROWS*4;
    hipFuncSetAttribute((const void*)odernn_kernel,
                        hipFuncAttributeMaxDynamicSharedMemorySize, smem_bytes);

    hipLaunchKernelGGL(prep_kernel, dim3(256), dim3(256), 0, stream,
                       Wih, Whh, W1, W2, W3, ws);
    hipLaunchKernelGGL(odernn_kernel, dim3(Bsz/ROWS), dim3(NWAVE*64), smem_bytes, stream,
                       x, tarr, mask, bih, bhh, b1, b2, b3, ws, out);
}

// Round 3
// 8525.700 us; speedup vs baseline: 1.3018x; 1.0368x over previous
//
#include <hip/hip_runtime.h>

#define Bsz 1024
#define Tn  200
#define Dd  64
#define Ld  256
#define Hd  256

#define ROWS   16          // batch rows per workgroup -> 64 WGs
#define NWAVE  8           // waves per WG (512 threads)
#define NTILE  2           // 16-col output tiles per wave (8*2*16 = 256 cols)
#define SA     264         // bf16 row stride for activation LDS (132 words = 4 mod 32 -> 2-way reads)
#define SX     72          // bf16 row stride for x tile

typedef __attribute__((ext_vector_type(8))) short  short8;
typedef __attribute__((ext_vector_type(4))) float  floatx4;

// workspace layout (bytes)
#define OFF_W1R  0                         // W1 per-wave reg layout        131072
#define OFF_W1L  (OFF_W1R + Ld*Ld*2)       // fp32 last col of W1             1024
#define OFF_W2R  (OFF_W1L + Hd*4)          // W2 per-wave reg layout        131072
#define OFF_W3R  (OFF_W2R + Hd*Hd*2)       // W3 per-wave reg layout        131072
#define OFF_WIHR (OFF_W3R + Ld*Hd*2)       // Wih per-wave layout            98304
#define OFF_WHHR (OFF_WIHR + 3*Ld*Dd*2)    // Whh per-wave layout           393216

__device__ __forceinline__ short f2bf(float f) {       // RNE (prep only)
    union { float f; unsigned u; } v; v.f = f;
    unsigned r = v.u + 0x7fffu + ((v.u >> 16) & 1u);
    return (short)(r >> 16);
}
__device__ __forceinline__ short f2bh(float f) {       // cheap round-half-up (hot path)
    union { float f; unsigned u; } v; v.f = f;
    return (short)((v.u + 0x8000u) >> 16);
}
__device__ __forceinline__ float sig_(float x) {
    float e = __expf(-x);                  // x->-inf: rcp(inf)=0, safe
    return __builtin_amdgcn_rcpf(1.f + e);
}
__device__ __forceinline__ float tanh_(float x) {
    // 1 - 2/(e^{2x}+1): e=inf -> 1; e=0 -> -1. No clamp needed.
    float e = __expf(2.f * x);
    return 1.f - 2.f * __builtin_amdgcn_rcpf(e + 1.f);
}
__device__ __forceinline__ floatx4 mfma_(short8 a, short8 b, floatx4 c) {
    return __builtin_amdgcn_mfma_f32_16x16x32_bf16(a, b, c, 0, 0, 0);
}

// ---------------- weight prep: fp32 -> bf16, reordered layouts ----------------
__global__ void prep_kernel(const float* __restrict__ Wih,
                            const float* __restrict__ Whh,
                            const float* __restrict__ W1,
                            const float* __restrict__ W2,
                            const float* __restrict__ W3,
                            char* __restrict__ ws)
{
    short* w1r  = (short*)(ws + OFF_W1R);
    float* w1l  = (float*)(ws + OFF_W1L);
    short* w2r  = (short*)(ws + OFF_W2R);
    short* w3r  = (short*)(ws + OFF_W3R);
    short* wihr = (short*)(ws + OFF_WIHR);
    short* whhr = (short*)(ws + OFF_WHHR);
    const int i0 = blockIdx.x * blockDim.x + threadIdx.x;
    const int stride = gridDim.x * blockDim.x;

    // W1R/W2R/W3R: idx = (((wv*2+jt)*8+ks)*64 + lane)*8 + jj
    for (int idx = i0; idx < Hd*Hd; idx += stride) {
        int jj = idx & 7, t = idx >> 3;
        int lane = t & 63; t >>= 6;
        int ks = t & 7; t >>= 3;
        int jt = t & 1, wv = t >> 1;
        int c16 = lane & 15, quad = lane >> 4;
        int col = wv*32 + jt*16 + c16, k = ks*32 + quad*8 + jj;
        w1r[idx] = f2bf(W1[col*(Ld+1) + k]);
        w2r[idx] = f2bf(W2[col*Hd + k]);
        w3r[idx] = f2bf(W3[col*Hd + k]);
    }
    for (int i = i0; i < Hd; i += stride) w1l[i] = W1[i*(Ld+1) + Ld];

    // WIHR: idx = ((((g*8+wv)*2+jt)*2+ks)*64 + lane)*8 + jj   (ks<2)
    for (int idx = i0; idx < 3*Ld*Dd; idx += stride) {
        int jj = idx & 7, t = idx >> 3;
        int lane = t & 63; t >>= 6;
        int ks = t & 1; t >>= 1;
        int jt = t & 1; t >>= 1;
        int wv = t & 7, g = t >> 3;
        int c16 = lane & 15, quad = lane >> 4;
        int col = wv*32 + jt*16 + c16, k = ks*32 + quad*8 + jj;
        wihr[idx] = f2bf(Wih[(g*Ld + col)*Dd + k]);
    }
    // WHHR: idx = ((((g*8+wv)*2+jt)*8+ks)*64 + lane)*8 + jj
    for (int idx = i0; idx < 3*Ld*Ld; idx += stride) {
        int jj = idx & 7, t = idx >> 3;
        int lane = t & 63; t >>= 6;
        int ks = t & 7; t >>= 3;
        int jt = t & 1; t >>= 1;
        int wv = t & 7, g = t >> 3;
        int c16 = lane & 15, quad = lane >> 4;
        int col = wv*32 + jt*16 + c16, k = ks*32 + quad*8 + jj;
        whhr[idx] = f2bf(Whh[(g*Ld + col)*Ld + k]);
    }
}

// ---------------- persistent ODE-RNN kernel ----------------
__global__ __launch_bounds__(NWAVE*64, 2) void odernn_kernel(
    const float* __restrict__ x,    const float* __restrict__ tarr,
    const float* __restrict__ mask,
    const float* __restrict__ b_ih, const float* __restrict__ b_hh,
    const float* __restrict__ b1v,  const float* __restrict__ b2v,
    const float* __restrict__ b3v,  const char* __restrict__ ws,
    float* __restrict__ out)
{
    __shared__ __attribute__((aligned(16))) short ays[ROWS*SA];
    __shared__ __attribute__((aligned(16))) short bu [ROWS*SA];
    __shared__ __attribute__((aligned(16))) short cv [ROWS*SA];
    __shared__ __attribute__((aligned(16))) short xb [ROWS*SX];
    __shared__ float maskv[ROWS];

    const short* WIHR = (const short*)(ws + OFF_WIHR);
    const short* WHHR = (const short*)(ws + OFF_WHHR);
    const float* W1l  = (const float*)(ws + OFF_W1L);

    const int tid  = threadIdx.x;
    const int wv   = tid >> 6;
    const int lane = tid & 63;
    const int quad = lane >> 4;
    const int c16  = lane & 15;
    const int koff = quad * 8;
    const int b0   = blockIdx.x * ROWS;
    const int aoff = c16*SA + koff;         // A-frag base (shorts)

    // preload W1/W2/W3 slices into registers: 3 x 16 short8 = 192 VGPRs
    short8 w1r[NTILE][8], w2r[NTILE][8], w3r[NTILE][8];
    {
        const short* W1R = (const short*)(ws + OFF_W1R);
        const short* W2R = (const short*)(ws + OFF_W2R);
        const short* W3R = (const short*)(ws + OFF_W3R);
#pragma unroll
        for (int jt = 0; jt < NTILE; ++jt)
#pragma unroll
            for (int ks = 0; ks < 8; ++ks) {
                int off = (((wv*NTILE + jt)*8 + ks)*64 + lane)*8;
                w1r[jt][ks] = *(const short8*)(W1R + off);
                w2r[jt][ks] = *(const short8*)(W2R + off);
                w3r[jt][ks] = *(const short8*)(W3R + off);
            }
    }

    // per-lane loop-invariant columns and MLP biases (GRU biases reloaded per step)
    int   ccol[NTILE];
    float b1c[NTILE], b2c[NTILE], b3c[NTILE], w1lc[NTILE];
#pragma unroll
    for (int jt = 0; jt < NTILE; ++jt) {
        int c = wv * (16*NTILE) + jt*16 + c16;
        ccol[jt] = c;
        b1c[jt]  = b1v[c]; b2c[jt] = b2v[c]; b3c[jt] = b3v[c];
        w1lc[jt] = W1l[c];
    }

    // fp32 hidden state: lane owns (row=quad*4+i, col=ccol[jt])
    float hreg[NTILE][4];
#pragma unroll
    for (int jt = 0; jt < NTILE; ++jt)
#pragma unroll
        for (int i = 0; i < 4; ++i) hreg[jt][i] = 0.f;

    for (int i = tid; i < ROWS*SA; i += NWAVE*64) ays[i] = 0;  // bf16(h=0)
    __syncthreads();

    for (int t = 0; t < Tn; ++t) {
        // ---- stage x tile + mask ----
        for (int i = tid; i < ROWS*Dd; i += NWAVE*64) {
            int r = i >> 6, d = i & 63;
            xb[r*SX + d] = f2bf(x[((size_t)(b0 + r)*Tn + t)*Dd + d]);
        }
        if (tid < ROWS) maskv[tid] = mask[(size_t)(b0 + tid)*Tn + t];
        __syncthreads();

        // ---- GRU per tile: accumulate gates, compute h_obs, stash (no ays writes yet) ----
        float hobs_s[NTILE][4];
#pragma unroll
        for (int jt = 0; jt < NTILE; ++jt) {
            floatx4 z4 = {0.f,0.f,0.f,0.f};
            floatx4 ar = z4, az = z4, ain = z4, ahn = z4;
#pragma unroll
            for (int ks = 0; ks < 2; ++ks) {
                short8 a = *(const short8*)&xb[c16*SX + ks*32 + koff];
                const short* p = WIHR + wv*2048 + jt*1024 + ks*512 + lane*8;
                ar  = mfma_(a, *(const short8*)(p),         ar);
                az  = mfma_(a, *(const short8*)(p + 16384), az);
                ain = mfma_(a, *(const short8*)(p + 32768), ain);
            }
#pragma unroll 1
            for (int ks = 0; ks < 8; ++ks) {
                short8 a = *(const short8*)&ays[aoff + ks*32];
                const short* p = WHHR + wv*8192 + jt*4096 + ks*512 + lane*8;
                ar  = mfma_(a, *(const short8*)(p),          ar);
                az  = mfma_(a, *(const short8*)(p + 65536),  az);
                ahn = mfma_(a, *(const short8*)(p + 131072), ahn);
            }
            int c = ccol[jt];
            float birv = b_ih[c]      + b_hh[c];
            float bizv = b_ih[Ld+c]   + b_hh[Ld+c];
            float binv = b_ih[2*Ld+c];
            float bhnv = b_hh[2*Ld+c];
#pragma unroll
            for (int i = 0; i < 4; ++i) {
                float hold = hreg[jt][i];
                float r = sig_(ar[i] + birv);
                float z = sig_(az[i] + bizv);
                float n = tanh_(ain[i] + binv + r*(ahn[i] + bhnv));
                float hnew = (1.f - z)*n + z*hold;
                float m = maskv[quad*4 + i];
                hobs_s[jt][i] = m*hnew + (1.f - m)*hold;
            }
        }
        __syncthreads();   // all waves finished reading ays

        // ---- write-back h_obs: state regs + bf16 mirror + global out ----
#pragma unroll
        for (int jt = 0; jt < NTILE; ++jt)
#pragma unroll
            for (int i = 0; i < 4; ++i) {
                int row = quad*4 + i;
                float hobs = hobs_s[jt][i];
                hreg[jt][i] = hobs;
                ays[row*SA + ccol[jt]] = f2bh(hobs);
                out[((size_t)(b0+row)*Tn + t)*Ld + ccol[jt]] = hobs;
            }
        __syncthreads();

        if (t == Tn - 1) break;   // last step: GRU only (h_fin)

        const float t0 = tarr[t];
        const float t1 = tarr[t+1];
        const float dt = (t1 - t0) * 0.25f;
        float kacc[NTILE][4];

#pragma unroll 1
        for (int sub = 0; sub < 4; ++sub) {
            const float tt = t0 + dt * (float)sub;
#pragma unroll
            for (int jt = 0; jt < NTILE; ++jt)
#pragma unroll
                for (int i = 0; i < 4; ++i) kacc[jt][i] = 0.f;

#pragma unroll 1
            for (int s = 0; s < 4; ++s) {
                const float tv = tt + ((s==0) ? 0.f : (s==3) ? dt : 0.5f*dt);
                floatx4 acc[NTILE];

                // ---- L1: u = tanh(y @ W1^T + tv*w1last + b1), W1 in regs ----
#pragma unroll
                for (int jt = 0; jt < NTILE; ++jt) { floatx4 z4 = {0.f,0.f,0.f,0.f}; acc[jt] = z4; }
#pragma unroll
                for (int ks = 0; ks < 8; ++ks) {
                    short8 a = *(const short8*)&ays[aoff + ks*32];
#pragma unroll
                    for (int jt = 0; jt < NTILE; ++jt)
                        acc[jt] = mfma_(a, w1r[jt][ks], acc[jt]);
                }
#pragma unroll
                for (int jt = 0; jt < NTILE; ++jt)
#pragma unroll
                    for (int i = 0; i < 4; ++i) {
                        float u = tanh_(acc[jt][i] + tv*w1lc[jt] + b1c[jt]);
                        bu[(quad*4+i)*SA + ccol[jt]] = f2bh(u);
                    }
                __syncthreads();

                // ---- L2: v = tanh(u @ W2^T + b2), W2 in regs ----
#pragma unroll
                for (int jt = 0; jt < NTILE; ++jt) { floatx4 z4 = {0.f,0.f,0.f,0.f}; acc[jt] = z4; }
#pragma unroll
                for (int ks = 0; ks < 8; ++ks) {
                    short8 a = *(const short8*)&bu[aoff + ks*32];
#pragma unroll
                    for (int jt = 0; jt < NTILE; ++jt)
                        acc[jt] = mfma_(a, w2r[jt][ks], acc[jt]);
                }
#pragma unroll
                for (int jt = 0; jt < NTILE; ++jt)
#pragma unroll
                    for (int i = 0; i < 4; ++i) {
                        float v = tanh_(acc[jt][i] + b2c[jt]);
                        cv[(quad*4+i)*SA + ccol[jt]] = f2bh(v);
                    }
                __syncthreads();

                // ---- L3: k = v @ W3^T + b3, W3 in regs; RK4 bookkeeping ----
#pragma unroll
                for (int jt = 0; jt < NTILE; ++jt) { floatx4 z4 = {0.f,0.f,0.f,0.f}; acc[jt] = z4; }
#pragma unroll
                for (int ks = 0; ks < 8; ++ks) {
                    short8 a = *(const short8*)&cv[aoff + ks*32];
#pragma unroll
                    for (int jt = 0; jt < NTILE; ++jt)
                        acc[jt] = mfma_(a, w3r[jt][ks], acc[jt]);
                }
                // ays last read in L1 (two barriers ago) -> safe to overwrite
                {
                    const float wst  = (s==1 || s==2) ? 2.f : 1.f;
                    const float coef = (s==2) ? dt : 0.5f*dt;
#pragma unroll
                    for (int jt = 0; jt < NTILE; ++jt)
#pragma unroll
                        for (int i = 0; i < 4; ++i) {
                            float k = acc[jt][i] + b3c[jt];
                            kacc[jt][i] += wst * k;
                            float ynext;
                            if (s < 3) {
                                ynext = hreg[jt][i] + coef * k;
                            } else {
                                ynext = hreg[jt][i] + (dt * (1.f/6.f)) * kacc[jt][i];
                                hreg[jt][i] = ynext;
                            }
                            ays[(quad*4+i)*SA + ccol[jt]] = f2bh(ynext);
                        }
                }
                __syncthreads();
            } // stages
        } // substeps
    } // t
}

extern "C" void kernel_launch(void* const* d_in, const int* in_sizes, int n_in,
                              void* d_out, int out_size, void* d_ws, size_t ws_size,
                              hipStream_t stream) {
    (void)in_sizes; (void)n_in; (void)out_size; (void)ws_size;
    const float* x    = (const float*)d_in[0];
    const float* tarr = (const float*)d_in[1];
    const float* mask = (const float*)d_in[2];
    const float* Wih  = (const float*)d_in[3];
    const float* Whh  = (const float*)d_in[4];
    const float* bih  = (const float*)d_in[5];
    const float* bhh  = (const float*)d_in[6];
    const float* W1   = (const float*)d_in[7];
    const float* b1   = (const float*)d_in[8];
    const float* W2   = (const float*)d_in[9];
    const float* b2   = (const float*)d_in[10];
    const float* W3   = (const float*)d_in[11];
    const float* b3   = (const float*)d_in[12];
    float* out = (float*)d_out;
    char*  ws  = (char*)d_ws;

    hipLaunchKernelGGL(prep_kernel, dim3(256), dim3(256), 0, stream,
                       Wih, Whh, W1, W2, W3, ws);
    hipLaunchKernelGGL(odernn_kernel, dim3(Bsz/ROWS), dim3(NWAVE*64), 0, stream,
                       x, tarr, mask, bih, bhh, b1, b2, b3, ws, out);
}